// Round 5
// baseline (9327.077 us; speedup 1.0000x reference)
//
#include <hip/hip_runtime.h>
#include <hip/hip_bf16.h>
#include <stdint.h>

// ============================================================================
// DaleConstrainedIntegrator: s_t = mask*clip((s_{t-1}+mask*ext_t) @ Weff^T),
// o0/o1 = dec{0,1}·s_t.  N=2048, B=128, T=1024.
//
// R4 (resubmit; R4's bench slot hit GPUAcquisitionTimeout — no data).
// vs R3 (6.98 ms == R2's 7.14 ms despite sync restructure): both rounds
// saturate ~4.8 TB/s of coherent (sc0sc1 -> LLC/fabric) A-fragment traffic:
// 64 column-tiles x 128 batches x 2048 x 2B = 32 MB/step. The fix is fewer,
// FATTER column tiles: 64 cols/WG halves traffic to 16 MB/step.
//   * 128 WGs: p = wg&3 (32 batches), q = wg>>2 (64 neurons/cols).
//   * Weff cols i0..i0+31: LDS (128 KB, XOR-slot swizzle, as R3).
//     Weff cols i0+32..i0+63: REGISTERS (per wave: its 16-kt K-range of
//     B-frags = 64 VGPRs, loaded once at init).
//   * Each A-frag feeds TWO MFMAs (acc0 via LDS-B, acc1 via reg-B).
//   * Reduce tree (8->4->2->1) runs twice, pass-separated by an extra
//     __syncthreads (safe red-slot reuse). wave0 finalizes both 32-col
//     halves: clip/mask, nsbuf, sc0sc1 ushort state stores w/ folded ext,
//     vmcnt(0), single arrive per WG.
//   * Sync: ctr[p][w] monotonic; consumer wave w needs producers q in
//     [4w,4w+4) => target 4t. Same WAR proof as R3 (arrive implies the
//     whole producer WG finished its step-t A-loads).
// ============================================================================

#define NN 2048
#define BB 128
#define TT 1024

typedef __attribute__((ext_vector_type(8)))  __bf16          bf16x8;
typedef __attribute__((ext_vector_type(8)))  unsigned short  ushort8;
typedef __attribute__((ext_vector_type(16))) float           f32x16;

// ws layout (bytes)
#define IF_OFF   0u              // ushort I[2][4][128][64][8] = 1 MB
#define IF_FRAGS 32768           // bf16x8 frags per parity (4*128*64)
#define CTR_OFF  (1u << 20)      // uint ctr[4][8][16] (64B lines) = 2 KB
#define CTR_BYTES 2048u

__device__ __forceinline__ unsigned short f2bf(float f) {
    __hip_bfloat16 h = __float2bfloat16(f);
    return *reinterpret_cast<unsigned short*>(&h);
}

union CV8 { ushort8 u; bf16x8 b; };

// ---------------------------------------------------------------------------
// Build I_0 = state0 + mask*(enc0*x0[:,0] + enc1*x1[:,0]), frag-packed.
// ---------------------------------------------------------------------------
__global__ void init_pack(const float* __restrict__ x0, const float* __restrict__ x1,
                          const float* __restrict__ enc0, const float* __restrict__ enc1,
                          const float* __restrict__ mask, const float* __restrict__ state0,
                          unsigned short* __restrict__ If)
{
    int idx  = blockIdx.x * 256 + threadIdx.x;        // 0 .. 262143
    int e    = idx & 7;
    int lane = (idx >> 3) & 63;
    int kt   = (idx >> 9) & 127;
    int p    = idx >> 16;
    int b    = p * 32 + (lane & 31);
    int j    = kt * 16 + ((lane >> 5) << 3) + e;
    float v  = state0[j] + mask[j] * (enc0[j] * x0[(size_t)b * TT]
                                    + enc1[j] * x1[(size_t)b * TT]);
    If[idx] = f2bf(v);
}

// ---------------------------------------------------------------------------
// LDS layout (bytes):
//   [0, 131072)        Wl   : swizzled bf16 [32 rows][2048]
//   [131072, +17408)   red  : float[4][64][17]
//   [148480, +8448)    nsbuf: float[32][66]     (32 batches x 64 cols + pad)
//   [156928, +1280)    ldsC : float[5][64]      mask,dec0,dec1,enc0,enc1
//   [158208, +256)     xbuf : float[2][32]
// total 158464 B
// ---------------------------------------------------------------------------
#define LDS_TOTAL 158464

__global__ void __launch_bounds__(512, 2)
dale_persistent(const float* __restrict__ x0, const float* __restrict__ x1,
                const float* __restrict__ enc0, const float* __restrict__ enc1,
                const float* __restrict__ dec0, const float* __restrict__ dec1,
                const float* __restrict__ W, const float* __restrict__ signs,
                const float* __restrict__ mask,
                unsigned short* __restrict__ If,
                unsigned int* __restrict__ ctr,
                float* __restrict__ out)
{
    extern __shared__ char lds[];
    float* red   = reinterpret_cast<float*>(lds + 131072);
    float* nsbuf = reinterpret_cast<float*>(lds + 148480);
    float* ldsC  = reinterpret_cast<float*>(lds + 156928);
    float* xbuf  = reinterpret_cast<float*>(lds + 158208);

    const int tid  = threadIdx.x;
    const int wave = tid >> 6;
    const int lane = tid & 63;
    const int wg   = blockIdx.x;
    const int p  = wg & 3;                 // 0..3  batch chunk (32 batches)
    const int q  = wg >> 2;                // 0..31 neuron chunk (64 cols)
    const int b0 = p * 32;
    const int i0 = q * 64;

    const int il = lane & 31;
    const int hi = lane >> 5;

    // ---- one-time: reg-resident Weff rows i0+32..i0+63 (B-frags, this
    //      wave's K-range kt = wave*16 .. +16)
    bf16x8 breg[16];
    {
        const int row = i0 + 32 + il;
        const float* wrow_g = W + (size_t)row * NN;
        #pragma unroll
        for (int it = 0; it < 16; ++it) {
            int kb = (wave * 16 + it) * 16 + hi * 8;
            const float* wr = wrow_g + kb;
            const float* sg = signs + kb;
            CV8 cv;
            #pragma unroll
            for (int e = 0; e < 8; ++e) cv.u[e] = f2bf(wr[e] * sg[e]);
            breg[it] = cv.b;
        }
    }

    // ---- one-time: LDS Weff rows i0..i0+31 (bf16, signs folded, swizzled)
    for (int o = tid; o < 8192; o += 512) {
        int il8 = o >> 8;
        int k8  = o & 255;
        const float* wr = W + (size_t)(i0 + il8) * NN + k8 * 8;
        const float* sg = signs + k8 * 8;
        ushort8 pk;
        #pragma unroll
        for (int e = 0; e < 8; ++e) pk[e] = f2bf(wr[e] * sg[e]);
        int slot = k8 ^ il8;
        *reinterpret_cast<ushort8*>(lds + il8 * 4096 + slot * 16) = pk;
    }
    if (tid < 64) {
        ldsC[tid]        = mask[i0 + tid];
        ldsC[64 + tid]   = dec0[i0 + tid];
        ldsC[128 + tid]  = dec1[i0 + tid];
        ldsC[192 + tid]  = enc0[i0 + tid];
        ldsC[256 + tid]  = enc1[i0 + tid];
    }
    __syncthreads();

    char* wrow = lds + il * 4096;

    // ---- hoisted per-thread constants
    const bf16x8* ApBase = reinterpret_cast<const bf16x8*>(If)
                         + (p * 128 + wave * 16) * 64 + lane;
    unsigned int* waitCtr = ctr + ((p * 8 + wave) << 4);
    unsigned int* arrCtr  = ctr + ((p * 8 + (q >> 2)) << 4);

    // finalize constants (wave0 uses)
    const float mkA  = ldsC[il],        mkB  = ldsC[32 + il];
    const float e0A  = ldsC[192 + il],  e0B  = ldsC[224 + il];
    const float e1A  = ldsC[256 + il],  e1B  = ldsC[288 + il];
    const int jA = i0 + il, jB = i0 + 32 + il;
    unsigned short* sbA = If + ((size_t)(p * 128 + (jA >> 4)) * 64) * 8
                        + (jA & 7) + ((jA >> 3) & 1) * 256;
    unsigned short* sbB = If + ((size_t)(p * 128 + (jB >> 4)) * 64) * 8
                        + (jB & 7) + ((jB >> 3) & 1) * 256;

    // epilogue constants: thread covers batch eb, cols ec..ec+3
    const int eb = tid >> 4;
    const int ec = (tid & 15) * 4;
    const float d00 = ldsC[64 + ec],  d01 = ldsC[64 + ec + 1];
    const float d02 = ldsC[64 + ec + 2], d03 = ldsC[64 + ec + 3];
    const float d10 = ldsC[128 + ec], d11 = ldsC[128 + ec + 1];
    const float d12 = ldsC[128 + ec + 2], d13 = ldsC[128 + ec + 3];
    float* out0 = out + (size_t)(b0 + eb) * TT;
    float* out1 = out + (size_t)BB * TT + (size_t)(b0 + eb) * TT;

    for (int t = 0; t < TT; ++t) {
        const int par = t & 1;

        // ---- wait for OUR K-range's 4 producer WGs (1 arrival each/step)
        if (t > 0) {
            const unsigned tgt = 4u * (unsigned)t;
            int guard = 0;
            for (;;) {
                unsigned vv = 0;
                if (lane == 0)
                    vv = __hip_atomic_load(waitCtr, __ATOMIC_RELAXED,
                                           __HIP_MEMORY_SCOPE_AGENT);
                unsigned v = (unsigned)__shfl((int)vv, 0, 64);
                if (v >= tgt || ++guard >= (1 << 17)) break;
                __builtin_amdgcn_s_sleep(1);
            }
        }

        // ---- x(t+1) prefetch into LDS (wave7; consumed by wave0 after syncs)
        if (wave == 7) {
            int bb = lane & 31;
            const float* xs = (lane < 32) ? x0 : x1;
            float v = (t + 1 < TT) ? xs[(size_t)(b0 + bb) * TT + (t + 1)] : 0.f;
            xbuf[hi * 32 + bb] = v;
        }

        // ---- A-fragment loads (coherent, LLC-sourced)
        bf16x8 A[16];
        const bf16x8* ap = ApBase + (size_t)par * IF_FRAGS;
        #pragma unroll
        for (int it = 0; it < 16; ++it) {
            const bf16x8* aptr = ap + it * 64;
            asm volatile("global_load_dwordx4 %0, %1, off sc0 sc1"
                         : "=v"(A[it]) : "v"(aptr) : "memory");
        }

        f32x16 acc0, acc1;
        #pragma unroll
        for (int r = 0; r < 16; ++r) { acc0[r] = 0.f; acc1[r] = 0.f; }

        asm volatile("s_waitcnt vmcnt(8)" ::: "memory");
        __builtin_amdgcn_sched_barrier(0);
        #pragma unroll
        for (int it = 0; it < 8; ++it) {
            int kt   = wave * 16 + it;
            int slot = (kt * 2 + hi) ^ il;
            bf16x8 bl = *reinterpret_cast<const bf16x8*>(wrow + slot * 16);
            acc0 = __builtin_amdgcn_mfma_f32_32x32x16_bf16(A[it], bl, acc0, 0, 0, 0);
            acc1 = __builtin_amdgcn_mfma_f32_32x32x16_bf16(A[it], breg[it], acc1, 0, 0, 0);
        }
        asm volatile("s_waitcnt vmcnt(0)" ::: "memory");
        __builtin_amdgcn_sched_barrier(0);
        #pragma unroll
        for (int it = 8; it < 16; ++it) {
            int kt   = wave * 16 + it;
            int slot = (kt * 2 + hi) ^ il;
            bf16x8 bl = *reinterpret_cast<const bf16x8*>(wrow + slot * 16);
            acc0 = __builtin_amdgcn_mfma_f32_32x32x16_bf16(A[it], bl, acc0, 0, 0, 0);
            acc1 = __builtin_amdgcn_mfma_f32_32x32x16_bf16(A[it], breg[it], acc1, 0, 0, 0);
        }

        // ==== reduce+finalize PASS 0 (cols i0..i0+31, acc0) ====
        if (wave >= 4) {
            float* d = red + (wave - 4) * 1088 + lane * 17;
            #pragma unroll
            for (int r = 0; r < 16; ++r) d[r] = acc0[r];
        }
        __syncthreads();
        if (wave < 4) {
            const float* s = red + wave * 1088 + lane * 17;
            #pragma unroll
            for (int r = 0; r < 16; ++r) acc0[r] += s[r];
            if (wave >= 2) {
                float* d = red + wave * 1088 + lane * 17;
                #pragma unroll
                for (int r = 0; r < 16; ++r) d[r] = acc0[r];
            }
        }
        __syncthreads();
        if (wave == 0) {
            const float* s = red + 2 * 1088 + lane * 17;
            #pragma unroll
            for (int r = 0; r < 16; ++r) acc0[r] += s[r];
        } else if (wave == 1) {
            const float* s = red + 3 * 1088 + lane * 17;
            float* d = red + 1088 + lane * 17;
            #pragma unroll
            for (int r = 0; r < 16; ++r) { acc0[r] += s[r]; d[r] = acc0[r]; }
        }
        __syncthreads();
        if (wave == 0) {
            const float* s = red + 1088 + lane * 17;
            unsigned short* sb = sbA + ((par == 0) ? (size_t)IF_FRAGS * 8 : 0);
            #pragma unroll
            for (int r = 0; r < 16; ++r) {
                float raw  = acc0[r] + s[r];
                int   brow = (r & 3) + 8 * (r >> 2) + 4 * hi;
                float ns   = fminf(fmaxf(raw, 0.f), 1e8f) * mkA;
                nsbuf[brow * 66 + il] = ns;
                if (t + 1 < TT) {
                    float v = ns + mkA * (e0A * xbuf[brow] + e1A * xbuf[32 + brow]);
                    unsigned int pv = (unsigned int)f2bf(v);
                    const unsigned short* dst = sb + brow * 8;
                    asm volatile("global_store_short %0, %1, off sc0 sc1"
                                 :: "v"(dst), "v"(pv) : "memory");
                }
            }
        }
        __syncthreads();   // pass separation (red slot reuse safety)

        // ==== reduce+finalize PASS 1 (cols i0+32..i0+63, acc1) ====
        if (wave >= 4) {
            float* d = red + (wave - 4) * 1088 + lane * 17;
            #pragma unroll
            for (int r = 0; r < 16; ++r) d[r] = acc1[r];
        }
        __syncthreads();
        if (wave < 4) {
            const float* s = red + wave * 1088 + lane * 17;
            #pragma unroll
            for (int r = 0; r < 16; ++r) acc1[r] += s[r];
            if (wave >= 2) {
                float* d = red + wave * 1088 + lane * 17;
                #pragma unroll
                for (int r = 0; r < 16; ++r) d[r] = acc1[r];
            }
        }
        __syncthreads();
        if (wave == 0) {
            const float* s = red + 2 * 1088 + lane * 17;
            #pragma unroll
            for (int r = 0; r < 16; ++r) acc1[r] += s[r];
        } else if (wave == 1) {
            const float* s = red + 3 * 1088 + lane * 17;
            float* d = red + 1088 + lane * 17;
            #pragma unroll
            for (int r = 0; r < 16; ++r) { acc1[r] += s[r]; d[r] = acc1[r]; }
        }
        __syncthreads();
        if (wave == 0) {
            const float* s = red + 1088 + lane * 17;
            unsigned short* sb = sbB + ((par == 0) ? (size_t)IF_FRAGS * 8 : 0);
            #pragma unroll
            for (int r = 0; r < 16; ++r) {
                float raw  = acc1[r] + s[r];
                int   brow = (r & 3) + 8 * (r >> 2) + 4 * hi;
                float ns   = fminf(fmaxf(raw, 0.f), 1e8f) * mkB;
                nsbuf[brow * 66 + 32 + il] = ns;
                if (t + 1 < TT) {
                    float v = ns + mkB * (e0B * xbuf[brow] + e1B * xbuf[32 + brow]);
                    unsigned int pv = (unsigned int)f2bf(v);
                    const unsigned short* dst = sb + brow * 8;
                    asm volatile("global_store_short %0, %1, off sc0 sc1"
                                 :: "v"(dst), "v"(pv) : "memory");
                }
            }
            if (t + 1 < TT) {
                asm volatile("s_waitcnt vmcnt(0)" ::: "memory");
                if (lane == 0)
                    __hip_atomic_fetch_add(arrCtr, 1u, __ATOMIC_RELAXED,
                                           __HIP_MEMORY_SCOPE_AGENT);
            }
        }
        __syncthreads();   // nsbuf ready

        // ---- output epilogue (off critical path, after arrive)
        {
            const float* nsr = nsbuf + eb * 66 + ec;
            float n0 = nsr[0], n1 = nsr[1], n2 = nsr[2], n3 = nsr[3];
            float o0p = d00 * n0 + d01 * n1 + d02 * n2 + d03 * n3;
            float o1p = d10 * n0 + d11 * n1 + d12 * n2 + d13 * n3;
            #pragma unroll
            for (int m = 8; m >= 1; m >>= 1) {
                o0p += __shfl_xor(o0p, m);
                o1p += __shfl_xor(o1p, m);
            }
            if ((tid & 15) == 0) {
                atomicAdd(out0 + t, o0p);
                atomicAdd(out1 + t, o1p);
            }
        }
    }
}

// ---------------------------------------------------------------------------
extern "C" void kernel_launch(void* const* d_in, const int* in_sizes, int n_in,
                              void* d_out, int out_size, void* d_ws, size_t ws_size,
                              hipStream_t stream)
{
    (void)in_sizes; (void)n_in; (void)ws_size;
    const float* x0    = (const float*)d_in[0];
    const float* x1    = (const float*)d_in[1];
    const float* enc0  = (const float*)d_in[2];
    const float* enc1  = (const float*)d_in[3];
    const float* dec0  = (const float*)d_in[4];
    const float* dec1  = (const float*)d_in[5];
    const float* W     = (const float*)d_in[6];
    const float* signs = (const float*)d_in[7];
    const float* mask  = (const float*)d_in[8];
    const float* st0   = (const float*)d_in[9];

    unsigned short* If  = (unsigned short*)((char*)d_ws + IF_OFF);
    unsigned int*   ctr = (unsigned int*)((char*)d_ws + CTR_OFF);
    float*          out = (float*)d_out;

    hipMemsetAsync(d_out, 0, sizeof(float) * (size_t)out_size, stream);
    hipMemsetAsync(ctr, 0, CTR_BYTES, stream);

    init_pack<<<1024, 256, 0, stream>>>(x0, x1, enc0, enc1, mask, st0, If);

    hipFuncSetAttribute(reinterpret_cast<const void*>(&dale_persistent),
                        hipFuncAttributeMaxDynamicSharedMemorySize, LDS_TOTAL);
    dale_persistent<<<128, 512, LDS_TOTAL, stream>>>(
        x0, x1, enc0, enc1, dec0, dec1, W, signs, mask, If, ctr, out);
}